// Round 2
// baseline (257.163 us; speedup 1.0000x reference)
//
#include <hip/hip_runtime.h>
#include <hip/hip_fp16.h>

// dot_attention: out[b,n] = exp(diag*s - lse_n), s = (D/2)^-0.5 = 1/16.
// B=4, N=4096, D=512. Inputs fp32, output fp32.
// No fp32 MFMA on CDNA4 -> fp16 convert + mfma_f32_16x16x32_f16.
//
// R9: occupancy restructure. R8 (counted-vmcnt/setprio schedule) was exactly
// neutral vs R7 -> bottleneck is NOT barrier drain. Counters: MfmaUtil 36%,
// LDS pipe ~51%, VALU 20%, Occupancy 19% -> no pipe saturated = latency-
// bound at 2 waves/SIMD (2 blocks/CU x 4 waves, LDS+grid pinned).
//  - cs split 4 -> 8 (512 kv cols/block, NIT=16), block 256 -> 512 thr
//    (8 waves, 256 q-rows), grid (32,16)=512 blocks.
//  - LDS unchanged (2x32KB dbuf) -> 2 blocks/CU x 8 waves = 4 waves/SIMD.
//  - Per-FLOP LDS traffic invariant (M=32 rows/wave kept); kvp re-reads
//    halved; q re-reads doubled (q is 32MB, L3-resident).
//  - Keep R8's counted-vmcnt phases (neutral, not harmful); wave now owns
//    2 frags/half -> vmcnt batches of 2.
// Model: per CU tile-iter max(LDS 3072c, MFMA 2483c) with 4 waves/SIMD to
// hide latency -> ~45-55us lse vs 80us measured at 2 waves/SIMD.

typedef _Float16 f16x8 __attribute__((ext_vector_type(8)));  // MFMA A/B frag (4 VGPR)
typedef float    f32x4 __attribute__((ext_vector_type(4)));  // MFMA C/D frag

#define NB 4
#define NN 4096
#define ND 512
#define SCALE 0.0625f
#define LOG2E 1.4426950408889634f
#define NROWS (NB * NN)            // 16384
#define NCS 8                      // column splits
#define FRAG_B 1024                // bytes per packed fragment
#define GRP_B  16384               // bytes per 16-row group (16 frags)
#define TILE_B 32768               // 32-row tile = 2 groups
#define CPITCH 520                 // convert LDS row pitch (halfwords) = 1040 B
#define NIT 16                     // kv tiles per (b,cs): 512 rows / 32

__device__ __forceinline__ void gld16(const void* g, void* l) {
    __builtin_amdgcn_global_load_lds(
        (const __attribute__((address_space(1))) unsigned int*)g,
        (__attribute__((address_space(3))) unsigned int*)l, 16, 0, 0);
}

__device__ __forceinline__ f16x8 cvt8(float4 a, float4 b) {
    f16x8 r;
    r[0] = (_Float16)a.x; r[1] = (_Float16)a.y; r[2] = (_Float16)a.z; r[3] = (_Float16)a.w;
    r[4] = (_Float16)b.x; r[5] = (_Float16)b.y; r[6] = (_Float16)b.z; r[7] = (_Float16)b.w;
    return r;
}

__device__ __forceinline__ f16x8 cvt8s(float4 a, float4 b, float s) {
    f16x8 r;
    r[0] = (_Float16)(a.x * s); r[1] = (_Float16)(a.y * s);
    r[2] = (_Float16)(a.z * s); r[3] = (_Float16)(a.w * s);
    r[4] = (_Float16)(b.x * s); r[5] = (_Float16)(b.y * s);
    r[6] = (_Float16)(b.z * s); r[7] = (_Float16)(b.w * s);
    return r;
}

// ---- kernel 1: kv fp32 -> fp16, packed in B-frag order via LDS transpose.
__launch_bounds__(256)
__global__ void convert_kernel(const float* __restrict__ kv,
                               _Float16* __restrict__ kvp) {
    __shared__ _Float16 s[16 * CPITCH];
    const int g    = blockIdx.x;
    const int tid  = threadIdx.x;
    const int wid  = tid >> 6;
    const int lane = tid & 63;
    const int l15  = lane & 15;
    const int quad = lane >> 4;

    #pragma unroll
    for (int i = 0; i < 4; ++i) {
        const int r = wid * 4 + i;
        const float* src = kv + ((size_t)g * 16 + r) * ND + lane * 8;
        float4 a = *(const float4*)src;
        float4 b = *(const float4*)(src + 4);
        *(f16x8*)(s + r * CPITCH + lane * 8) = cvt8(a, b);
    }
    __syncthreads();

    _Float16* dst = kvp + (size_t)g * 8192 + lane * 8;
    #pragma unroll
    for (int p = 0; p < 4; ++p) {
        const int kt = wid * 4 + p;
        f16x8 v = *(const f16x8*)(s + l15 * CPITCH + kt * 32 + quad * 8);
        *(f16x8*)(dst + kt * 512) = v;
    }
}

// ---- kernel 2: per-row sum of exp(score) over a 512-column split + diag.
// grid (32: b*8+cs, 16: rowblock) = 512 blocks, 512 threads = 8 waves,
// 2 blocks/CU (2x32KB LDS dbuf) -> 16 waves/CU = 4 waves/SIMD. Wave: 32
// q-rows (Af 128 regs). Per iter: one 32-row kv tile shared by all 8 waves.
__launch_bounds__(512, 4)
__global__ void lse_partial_kernel(const float* __restrict__ q,
                                   const _Float16* __restrict__ kvp,
                                   float* __restrict__ partial,
                                   float* __restrict__ diagsc) {
    __shared__ char sbuf[2][TILE_B];

    const int bc = blockIdx.x;          // b*8 + cs (fastest -> x%8 = cs = XCD:
    const int b  = bc >> 3;             //   all rowblocks of a cs share an XCD)
    const int cs = bc & 7;
    const int rb = blockIdx.y;
    const int tid  = threadIdx.x;
    const int wid  = tid >> 6;          // 0..7
    const int lane = tid & 63;
    const int l15  = lane & 15;
    const int quad = lane >> 4;

    const int row0 = rb * 256 + wid * 32;    // wave's first q-row (in batch)
    // iteration whose 32-col kv tile coincides with this wave's 32 q-rows
    const int it_diag = ((row0 >> 9) == cs) ? ((row0 - cs * 512) >> 5) : -1;

    // packed base for this (b,cs): groups [b*256 + cs*32, +32) = 16 tiles
    const char* pb  = (const char*)kvp + ((size_t)(b * 256 + cs * 32)) * GRP_B;
    const char* ssb = pb + (size_t)lane * 16;

    char* cur = sbuf[0];
    char* nxt = sbuf[1];

    // stage one kt-half (h_=0: kt 0-7, h_=1: kt 8-15) of tile `it_`.
    // Wave w owns frag kt=h*8+w in BOTH groups -> 2 DMAs = one vmcnt batch.
    // LDS dest is wave-uniform base (HW adds lane*16); per-lane part lives
    // in the global source address (m104/m108).
    #define STAGE_HALF(h_, it_, dst_)                                          \
        do {                                                                   \
            const char* sp_ = ssb + (size_t)(it_) * TILE_B;                    \
            const int f_ = (h_) * 8 + wid;                                     \
            gld16(sp_ + (size_t)f_ * FRAG_B,                                   \
                  (dst_) + (size_t)f_ * FRAG_B);                               \
            gld16(sp_ + GRP_B + (size_t)f_ * FRAG_B,                           \
                  (dst_) + GRP_B + (size_t)f_ * FRAG_B);                       \
        } while (0)

    // issue tile-0 DMAs first so they land under the A-frag load/convert
    STAGE_HALF(0, 0, cur);
    STAGE_HALF(1, 0, cur);

    // ---- A fragments: q fp32 -> fp16 scaled by s*log2e (exp2 path).
    f16x8 Af[2][16];
    #pragma unroll
    for (int m = 0; m < 2; ++m) {
        const float* qrow = q + ((size_t)(b * NN + row0 + m * 16 + l15)) * ND + quad * 8;
        #pragma unroll
        for (int k = 0; k < 16; ++k) {
            float4 u0 = *(const float4*)(qrow + k * 32);
            float4 u1 = *(const float4*)(qrow + k * 32 + 4);
            Af[m][k] = cvt8s(u0, u1, SCALE * LOG2E);
        }
    }

    float lacc[2][4];
    #pragma unroll
    for (int m = 0; m < 2; ++m)
        #pragma unroll
        for (int j = 0; j < 4; ++j)
            lacc[m][j] = 0.f;

    #define MFMA_HALF(kt0_)                                                    \
        do {                                                                   \
            const char* lb_ = cur + (size_t)lane * 16;                         \
            _Pragma("unroll")                                                  \
            for (int kt = (kt0_); kt < (kt0_) + 8; ++kt) {                     \
                f16x8 b0 = *(const f16x8*)(lb_ + kt * FRAG_B);                 \
                f16x8 b1 = *(const f16x8*)(lb_ + GRP_B + kt * FRAG_B);         \
                acc[0][0] = __builtin_amdgcn_mfma_f32_16x16x32_f16(Af[0][kt], b0, acc[0][0], 0, 0, 0); \
                acc[1][0] = __builtin_amdgcn_mfma_f32_16x16x32_f16(Af[1][kt], b0, acc[1][0], 0, 0, 0); \
                acc[0][1] = __builtin_amdgcn_mfma_f32_16x16x32_f16(Af[0][kt], b1, acc[0][1], 0, 0, 0); \
                acc[1][1] = __builtin_amdgcn_mfma_f32_16x16x32_f16(Af[1][kt], b1, acc[1][1], 0, 0, 0); \
            }                                                                  \
        } while (0)

    for (int it = 0; it < NIT; ++it) {
        f32x4 acc[2][2];
        #pragma unroll
        for (int m = 0; m < 2; ++m)
            #pragma unroll
            for (int nf = 0; nf < 2; ++nf)
                acc[m][nf] = (f32x4){0.f, 0.f, 0.f, 0.f};

        // ---- phase A: kt 0-7 of cur; prefetch H0(it+1) into nxt.
        // outstanding: {H0(it):2, H1(it):2} -> vmcnt(2) == H0(it) landed
        // (own batch; the barrier makes it a cross-wave guarantee).
        asm volatile("s_waitcnt vmcnt(2)" ::: "memory");
        __builtin_amdgcn_s_barrier();
        asm volatile("" ::: "memory");     // pin ds_reads below the barrier
        if (it + 1 < NIT) STAGE_HALF(0, it + 1, nxt);
        __builtin_amdgcn_s_setprio(1);
        MFMA_HALF(0);
        __builtin_amdgcn_s_setprio(0);

        // ---- phase B: kt 8-15 of cur; prefetch H1(it+1) into nxt.
        // outstanding: {H1(it):2, H0(it+1):2} -> vmcnt(2) == H1(it) landed.
        if (it + 1 < NIT) {
            asm volatile("s_waitcnt vmcnt(2)" ::: "memory");
        } else {
            asm volatile("s_waitcnt vmcnt(0)" ::: "memory");  // last tile: drain
        }
        __builtin_amdgcn_s_barrier();
        asm volatile("" ::: "memory");
        if (it + 1 < NIT) STAGE_HALF(1, it + 1, nxt);
        __builtin_amdgcn_s_setprio(1);
        MFMA_HALF(8);
        __builtin_amdgcn_s_setprio(0);

        // diag extraction: C/D row = quad*4+j, col = nf*16+l15. On the
        // aligned iter, row==col  =>  nf==m, l15==quad*4+j.
        if (it == it_diag) {
            if ((l15 >> 2) == quad) {
                const int j = l15 & 3;
                float d0 = (j == 0) ? acc[0][0][0] : (j == 1) ? acc[0][0][1]
                         : (j == 2) ? acc[0][0][2] : acc[0][0][3];
                float d1 = (j == 0) ? acc[1][1][0] : (j == 1) ? acc[1][1][1]
                         : (j == 2) ? acc[1][1][2] : acc[1][1][3];
                diagsc[b * NN + row0 + l15]      = d0;   // score*log2e
                diagsc[b * NN + row0 + 16 + l15] = d1;
            }
        }

        // acc = score*log2e -> exp(score) = exp2(acc) = native v_exp_f32
        #pragma unroll
        for (int m = 0; m < 2; ++m)
            #pragma unroll
            for (int nf = 0; nf < 2; ++nf)
                #pragma unroll
                for (int j = 0; j < 4; ++j)
                    lacc[m][j] += __builtin_amdgcn_exp2f(acc[m][nf][j]);

        char* t = cur; cur = nxt; nxt = t;
    }

    // reduce over the 16 columns held across l15 lanes
    #pragma unroll
    for (int m = 0; m < 2; ++m)
        #pragma unroll
        for (int j = 0; j < 4; ++j) {
            float v = lacc[m][j];
            v += __shfl_xor(v, 1, 64);
            v += __shfl_xor(v, 2, 64);
            v += __shfl_xor(v, 4, 64);
            v += __shfl_xor(v, 8, 64);
            if (l15 == 0)
                partial[(size_t)cs * NROWS + b * NN + row0 + m * 16 + quad * 4 + j] = v;
        }
}

// ---- kernel 3: out = exp2(diag_scaled) / sum_cs partial
__launch_bounds__(256)
__global__ void finalize_kernel(const float* __restrict__ partial,
                                const float* __restrict__ diagsc,
                                float* __restrict__ out) {
    const int idx = blockIdx.x * 256 + threadIdx.x;
    float l = 0.f;
    #pragma unroll
    for (int c = 0; c < NCS; ++c)
        l += partial[(size_t)c * NROWS + idx];
    out[idx] = exp2f(diagsc[idx]) / l;
}

extern "C" void kernel_launch(void* const* d_in, const int* in_sizes, int n_in,
                              void* d_out, int out_size, void* d_ws, size_t ws_size,
                              hipStream_t stream) {
    const float* q  = (const float*)d_in[0];
    const float* kv = (const float*)d_in[1];
    float* out = (float*)d_out;

    // ws: kvp fp16 packed [16MB] | partial f32[8][16384] | diagsc f32[16384]
    _Float16* kvp   = (_Float16*)d_ws;
    float* partial  = (float*)((char*)d_ws + (size_t)NROWS * ND * 2);
    float* diagsc   = partial + NCS * NROWS;

    convert_kernel<<<1024, 256, 0, stream>>>(kv, kvp);
    lse_partial_kernel<<<dim3(32, 16), 512, 0, stream>>>(q, kvp, partial, diagsc);
    finalize_kernel<<<NROWS / 256, 256, 0, stream>>>(partial, diagsc, out);
}

// Round 3
// 162.336 us; speedup vs baseline: 1.5841x; 1.5841x over previous
//
#include <hip/hip_runtime.h>
#include <hip/hip_fp16.h>

// dot_attention: out[b,n] = exp(diag*s - lse_n), s = (D/2)^-0.5 = 1/16.
// B=4, N=4096, D=512. Inputs fp32, output fp32.
// No fp32 MFMA on CDNA4 -> fp16 convert + mfma_f32_16x16x32_f16.
//
// R10: R7 geometry + explicit 2-deep B-frag prefetch pipeline.
//  - R8 (counted-vmcnt/setprio): exactly neutral -> not barrier-bound.
//  - R9 (8-wave blocks, launch_bounds(512,4)): VGPR capped at 128 -> Af
//    spilled to scratch (VGPR 64, FETCH 530MB, 180us). Structural lesson:
//    A-resident M=32 needs ~220 regs -> 2 waves/SIMD is a hard ceiling.
//  - Counters (R7/R8): per CU-iter-pair LDS 3072c + MFMA 2483c ~= measured
//    6000c -> pipes SERIALIZE. With 2 waves/SIMD, each kt-step eats the
//    ~120cy LDS return latency (MfmaUtil 36% == depth-1 prefetch).
//  - Fix: software-pipeline B-frag ds_reads 2 kt-steps ahead (4 frags in
//    flight, static indices, +16 VGPR, occupancy unchanged).

typedef _Float16 f16x8 __attribute__((ext_vector_type(8)));  // MFMA A/B frag (4 VGPR)
typedef float    f32x4 __attribute__((ext_vector_type(4)));  // MFMA C/D frag

#define NB 4
#define NN 4096
#define ND 512
#define SCALE 0.0625f
#define LOG2E 1.4426950408889634f
#define NROWS (NB * NN)            // 16384
#define NCS 4                      // column splits
#define FRAG_B 1024                // bytes per packed fragment
#define GRP_B  16384               // bytes per 16-row group (16 frags)
#define TILE_B 32768               // 32-row tile = 2 groups
#define CPITCH 520                 // convert LDS row pitch (halfwords) = 1040 B
#define NIT 32                     // kv tiles per (b,cs): 1024 rows / 32

__device__ __forceinline__ void gld16(const void* g, void* l) {
    __builtin_amdgcn_global_load_lds(
        (const __attribute__((address_space(1))) unsigned int*)g,
        (__attribute__((address_space(3))) unsigned int*)l, 16, 0, 0);
}

__device__ __forceinline__ f16x8 cvt8(float4 a, float4 b) {
    f16x8 r;
    r[0] = (_Float16)a.x; r[1] = (_Float16)a.y; r[2] = (_Float16)a.z; r[3] = (_Float16)a.w;
    r[4] = (_Float16)b.x; r[5] = (_Float16)b.y; r[6] = (_Float16)b.z; r[7] = (_Float16)b.w;
    return r;
}

__device__ __forceinline__ f16x8 cvt8s(float4 a, float4 b, float s) {
    f16x8 r;
    r[0] = (_Float16)(a.x * s); r[1] = (_Float16)(a.y * s);
    r[2] = (_Float16)(a.z * s); r[3] = (_Float16)(a.w * s);
    r[4] = (_Float16)(b.x * s); r[5] = (_Float16)(b.y * s);
    r[6] = (_Float16)(b.z * s); r[7] = (_Float16)(b.w * s);
    return r;
}

// ---- kernel 1: kv fp32 -> fp16, packed in B-frag order via LDS transpose.
__launch_bounds__(256)
__global__ void convert_kernel(const float* __restrict__ kv,
                               _Float16* __restrict__ kvp) {
    __shared__ _Float16 s[16 * CPITCH];
    const int g    = blockIdx.x;
    const int tid  = threadIdx.x;
    const int wid  = tid >> 6;
    const int lane = tid & 63;
    const int l15  = lane & 15;
    const int quad = lane >> 4;

    #pragma unroll
    for (int i = 0; i < 4; ++i) {
        const int r = wid * 4 + i;
        const float* src = kv + ((size_t)g * 16 + r) * ND + lane * 8;
        float4 a = *(const float4*)src;
        float4 b = *(const float4*)(src + 4);
        *(f16x8*)(s + r * CPITCH + lane * 8) = cvt8(a, b);
    }
    __syncthreads();

    _Float16* dst = kvp + (size_t)g * 8192 + lane * 8;
    #pragma unroll
    for (int p = 0; p < 4; ++p) {
        const int kt = wid * 4 + p;
        f16x8 v = *(const f16x8*)(s + l15 * CPITCH + kt * 32 + quad * 8);
        *(f16x8*)(dst + kt * 512) = v;
    }
}

// ---- kernel 2: per-row sum of exp(score) over a 1024-column split + diag.
// grid (16: b*4+cs, 32: rowblock) = 512 blocks, 256 threads = 4 waves,
// 2 blocks/CU (2x32KB LDS dbuf), 2 waves/SIMD. Wave: 32 q-rows (Af 128
// regs). Per iter: one 32-row kv tile, B-frags prefetched 2 kt ahead.
__launch_bounds__(256, 2)
__global__ void lse_partial_kernel(const float* __restrict__ q,
                                   const _Float16* __restrict__ kvp,
                                   float* __restrict__ partial,
                                   float* __restrict__ diagsc) {
    __shared__ char sbuf[2][TILE_B];

    const int bc = blockIdx.x;          // b*4 + cs (fastest -> spread over XCDs)
    const int b  = bc >> 2;
    const int cs = bc & 3;
    const int rb = blockIdx.y;
    const int tid  = threadIdx.x;
    const int wid  = tid >> 6;
    const int lane = tid & 63;
    const int l15  = lane & 15;
    const int quad = lane >> 4;

    const int row0 = rb * 128 + wid * 32;    // wave's first q-row (in batch)
    // iteration whose 32-col kv tile coincides with this wave's 32 q-rows
    const int it_diag = ((row0 >> 10) == cs) ? ((row0 - cs * 1024) >> 5) : -1;

    // packed base for this (b,cs): groups [b*256 + cs*64, +64) = 32 tiles
    const char* pb  = (const char*)kvp + ((size_t)(b * 256 + cs * 64)) * GRP_B;
    const char* ssb = pb + (size_t)lane * 16;

    char* cur = sbuf[0];
    char* nxt = sbuf[1];

    // stage 32-frag tile `it_`: 8 frag-DMAs per wave. LDS dest is
    // wave-uniform base (HW adds lane*16); per-lane part lives in the
    // global source address (m104/m108).
    #define STAGE(it_, dst_)                                                  \
        do {                                                                  \
            const char* sp_ = ssb + (size_t)(it_) * TILE_B;                   \
            _Pragma("unroll")                                                 \
            for (int p_ = 0; p_ < 8; ++p_) {                                  \
                int f_ = wid * 8 + p_;                                        \
                gld16(sp_ + (size_t)f_ * FRAG_B, (dst_) + (size_t)f_ * FRAG_B); \
            }                                                                 \
        } while (0)

    // issue tile-0 DMAs first so they land under the A-frag load/convert
    STAGE(0, cur);

    // ---- A fragments: q fp32 -> fp16 scaled by s*log2e (exp2 path).
    f16x8 Af[2][16];
    #pragma unroll
    for (int m = 0; m < 2; ++m) {
        const float* qrow = q + ((size_t)(b * NN + row0 + m * 16 + l15)) * ND + quad * 8;
        #pragma unroll
        for (int k = 0; k < 16; ++k) {
            float4 u0 = *(const float4*)(qrow + k * 32);
            float4 u1 = *(const float4*)(qrow + k * 32 + 4);
            Af[m][k] = cvt8s(u0, u1, SCALE * LOG2E);
        }
    }

    float lacc[2][4];
    #pragma unroll
    for (int m = 0; m < 2; ++m)
        #pragma unroll
        for (int j = 0; j < 4; ++j)
            lacc[m][j] = 0.f;

    for (int it = 0; it < NIT; ++it) {
        f32x4 acc[2][2];
        #pragma unroll
        for (int m = 0; m < 2; ++m)
            #pragma unroll
            for (int nf = 0; nf < 2; ++nf)
                acc[m][nf] = (f32x4){0.f, 0.f, 0.f, 0.f};

        // tile-`it` DMA drained; all waves done READING `nxt` (it-1 compute)
        asm volatile("s_waitcnt vmcnt(0)" ::: "memory");
        __builtin_amdgcn_s_barrier();
        asm volatile("" ::: "memory");     // pin ds_reads below the barrier
        if (it + 1 < NIT) STAGE(it + 1, nxt);

        const char* lb = cur + (size_t)lane * 16;

        // ---- software-pipelined MFMA: B-frags read 2 kt-steps ahead.
        // Slot parity kt&1; all indices compile-time (rule #20). In-order
        // DS returns -> compiler waits lgkmcnt(4) per step (4 newer reads
        // outstanding), hiding the ~120cy LDS latency under 2 kt of MFMA.
        f16x8 pb0[2], pb1[2];
        pb0[0] = *(const f16x8*)(lb + 0 * FRAG_B);
        pb1[0] = *(const f16x8*)(lb + GRP_B + 0 * FRAG_B);
        pb0[1] = *(const f16x8*)(lb + 1 * FRAG_B);
        pb1[1] = *(const f16x8*)(lb + GRP_B + 1 * FRAG_B);

        __builtin_amdgcn_s_setprio(1);
        #define KSTEP(kt_)                                                     \
            do {                                                               \
                acc[0][0] = __builtin_amdgcn_mfma_f32_16x16x32_f16(            \
                    Af[0][kt_], pb0[(kt_) & 1], acc[0][0], 0, 0, 0);           \
                acc[1][0] = __builtin_amdgcn_mfma_f32_16x16x32_f16(            \
                    Af[1][kt_], pb0[(kt_) & 1], acc[1][0], 0, 0, 0);           \
                acc[0][1] = __builtin_amdgcn_mfma_f32_16x16x32_f16(            \
                    Af[0][kt_], pb1[(kt_) & 1], acc[0][1], 0, 0, 0);           \
                acc[1][1] = __builtin_amdgcn_mfma_f32_16x16x32_f16(            \
                    Af[1][kt_], pb1[(kt_) & 1], acc[1][1], 0, 0, 0);           \
                if ((kt_) + 2 < 16) {                                          \
                    pb0[(kt_) & 1] =                                           \
                        *(const f16x8*)(lb + ((kt_) + 2) * FRAG_B);            \
                    pb1[(kt_) & 1] =                                           \
                        *(const f16x8*)(lb + GRP_B + ((kt_) + 2) * FRAG_B);    \
                }                                                              \
            } while (0)
        KSTEP(0);  KSTEP(1);  KSTEP(2);  KSTEP(3);
        KSTEP(4);  KSTEP(5);  KSTEP(6);  KSTEP(7);
        KSTEP(8);  KSTEP(9);  KSTEP(10); KSTEP(11);
        KSTEP(12); KSTEP(13); KSTEP(14); KSTEP(15);
        #undef KSTEP
        __builtin_amdgcn_s_setprio(0);

        // diag extraction: C/D row = quad*4+j, col = nf*16+l15. On the
        // aligned iter, row==col  =>  nf==m, l15==quad*4+j.
        if (it == it_diag) {
            if ((l15 >> 2) == quad) {
                const int j = l15 & 3;
                float d0 = (j == 0) ? acc[0][0][0] : (j == 1) ? acc[0][0][1]
                         : (j == 2) ? acc[0][0][2] : acc[0][0][3];
                float d1 = (j == 0) ? acc[1][1][0] : (j == 1) ? acc[1][1][1]
                         : (j == 2) ? acc[1][1][2] : acc[1][1][3];
                diagsc[b * NN + row0 + l15]      = d0;   // score*log2e
                diagsc[b * NN + row0 + 16 + l15] = d1;
            }
        }

        // acc = score*log2e -> exp(score) = exp2(acc) = native v_exp_f32
        #pragma unroll
        for (int m = 0; m < 2; ++m)
            #pragma unroll
            for (int nf = 0; nf < 2; ++nf)
                #pragma unroll
                for (int j = 0; j < 4; ++j)
                    lacc[m][j] += __builtin_amdgcn_exp2f(acc[m][nf][j]);

        char* t = cur; cur = nxt; nxt = t;
    }

    // reduce over the 16 columns held across l15 lanes
    #pragma unroll
    for (int m = 0; m < 2; ++m)
        #pragma unroll
        for (int j = 0; j < 4; ++j) {
            float v = lacc[m][j];
            v += __shfl_xor(v, 1, 64);
            v += __shfl_xor(v, 2, 64);
            v += __shfl_xor(v, 4, 64);
            v += __shfl_xor(v, 8, 64);
            if (l15 == 0)
                partial[(size_t)cs * NROWS + b * NN + row0 + m * 16 + quad * 4 + j] = v;
        }
}

// ---- kernel 3: out = exp2(diag_scaled) / sum_cs partial
__launch_bounds__(256)
__global__ void finalize_kernel(const float* __restrict__ partial,
                                const float* __restrict__ diagsc,
                                float* __restrict__ out) {
    const int idx = blockIdx.x * 256 + threadIdx.x;
    float l = 0.f;
    #pragma unroll
    for (int c = 0; c < NCS; ++c)
        l += partial[(size_t)c * NROWS + idx];
    out[idx] = exp2f(diagsc[idx]) / l;
}

extern "C" void kernel_launch(void* const* d_in, const int* in_sizes, int n_in,
                              void* d_out, int out_size, void* d_ws, size_t ws_size,
                              hipStream_t stream) {
    const float* q  = (const float*)d_in[0];
    const float* kv = (const float*)d_in[1];
    float* out = (float*)d_out;

    // ws: kvp fp16 packed [16MB] | partial f32[4][16384] | diagsc f32[16384]
    _Float16* kvp   = (_Float16*)d_ws;
    float* partial  = (float*)((char*)d_ws + (size_t)NROWS * ND * 2);
    float* diagsc   = partial + NCS * NROWS;

    convert_kernel<<<1024, 256, 0, stream>>>(kv, kvp);
    lse_partial_kernel<<<dim3(16, 32), 256, 0, stream>>>(q, kvp, partial, diagsc);
    finalize_kernel<<<NROWS / 256, 256, 0, stream>>>(partial, diagsc, out);
}